// Round 9
// baseline (6447.272 us; speedup 1.0000x reference)
//
#include <hip/hip_runtime.h>
#include <hip/hip_bf16.h>
#include <stdint.h>

// Sizes from the reference
#define BS   256
#define T_   128
#define TP   127      // T-1
#define DD   128
#define DT   16
#define DB   32
#define DH   256
#define NH   4
#define DS   64
#define DHN  1024

#define OFFV (256u*127u*64u)   // size of each output tensor

typedef __attribute__((ext_vector_type(8))) short short8v;
typedef __attribute__((ext_vector_type(4))) float f32x4;
typedef __attribute__((ext_vector_type(2))) float f32x2;

__device__ __forceinline__ float bf16u(unsigned short u){ return __uint_as_float((unsigned)u << 16); }
__device__ __forceinline__ unsigned short f2bf(float f){
  unsigned u = __float_as_uint(f);
  u += 0x7fffu + ((u >> 16) & 1u);   // RNE
  return (unsigned short)(u >> 16);
}
__device__ __forceinline__ float softplus_f(float x){
  return fmaxf(x, 0.f) + log1pf(__expf(-fabsf(x)));
}
__device__ __forceinline__ unsigned pk4fp8(float f0, float f1, float f2, float f3){
  int pk8 = __builtin_amdgcn_cvt_pk_fp8_f32(f0, f1, 0, false);
  pk8     = __builtin_amdgcn_cvt_pk_fp8_f32(f2, f3, pk8, true);
  return (unsigned)pk8;
}
#define CVT8(w, hi) __builtin_amdgcn_cvt_pk_f32_fp8((w), (hi))

#define REP16(M) M(0) M(1) M(2) M(3) M(4) M(5) M(6) M(7) M(8) M(9) M(10) M(11) \
  M(12) M(13) M(14) M(15)

// ---------------------------------------------------------------------------
// Kernel 1: pack recurrent weights to fp8 (x64 pre-scale), coalesced layouts:
//  hvf[s4][j2] uint2 : bytes (s,j) pairs for 4 s x 2 cols        (64 KB)
//  hkf[s4][d]  uint  : 4 s's for key col d                        (16 KB)
//  msf[sel][j4][k] uint : 4 j's for output col k (mut,sgt)       (128 KB)
// ---------------------------------------------------------------------------
__global__ __launch_bounds__(256) void pack_w_kernel(
    const float* __restrict__ hk_w, const float* __restrict__ hv_w,
    const float* __restrict__ mut_w, const float* __restrict__ sgt_w,
    uint2* __restrict__ hvf, unsigned* __restrict__ hkf, unsigned* __restrict__ msf)
{
  int i = blockIdx.x * 256 + threadIdx.x;
  if (i < 8192) { int s4 = i >> 9, j2 = i & 511;
    const float* w0 = hv_w + (size_t)(4*s4)*1024 + 2*j2;
    uint2 u;
    u.x = pk4fp8(w0[0]*64.f, w0[1]*64.f, w0[1024]*64.f, w0[1025]*64.f);
    u.y = pk4fp8(w0[2048]*64.f, w0[2049]*64.f, w0[3072]*64.f, w0[3073]*64.f);
    hvf[i] = u; }
  if (i < 4096) { int s4 = i >> 8, d = i & 255;
    const float* w0 = hk_w + (size_t)(4*s4)*256 + d;
    hkf[i] = pk4fp8(w0[0]*64.f, w0[256]*64.f, w0[512]*64.f, w0[768]*64.f); }
  if (i < 32768) { int sel = i >> 14, j4 = (i >> 6) & 255, k = i & 63;
    const float* w = (sel ? sgt_w : mut_w) + (size_t)(4*j4)*64 + k;
    msf[i] = pk4fp8(w[0]*64.f, w[64]*64.f, w[128]*64.f, w[192]*64.f); }
}

// ---------------------------------------------------------------------------
// Kernel 2: projection GEMM (MFMA bf16 16x16x32).  One block per b.
// Emits fp8 directly:
//   Qf8[b][r=t*4+h] : 16 x uint4-chunks (256 d's)  -> register-resident later
//   Vf8[b][n][j2][d]: dword = col (2*j2+d), t=4n..4n+3 -> LDS-staged later
// ---------------------------------------------------------------------------
#define LDA 168

__global__ __launch_bounds__(256) void proj_kernel(
    const float* __restrict__ x, const float* __restrict__ a,
    const float* __restrict__ q_w, const float* __restrict__ q_b,
    const float* __restrict__ v_w, const float* __restrict__ v_b,
    uint4* __restrict__ Qf8, unsigned* __restrict__ Vf8)
{
  const int b    = blockIdx.x;
  const int tid  = threadIdx.x;
  const int lane = tid & 63;
  const int w    = tid >> 6;

  __shared__ __align__(16) unsigned short A_s[128 * LDA];
  __shared__ __align__(16) unsigned short BC_s[64 * LDA];

  for (int idx = tid; idx < 128 * DD; idx += 256) {
    int t = idx >> 7, k = idx & 127;
    float v = (t < TP) ? x[((size_t)b * T_ + 1 + t) * DD + k] : 0.f;
    A_s[t * LDA + k] = f2bf(v);
  }
  for (int idx = tid; idx < 128 * 40; idx += 256) {
    int t = idx / 40, kk = idx % 40;
    float v = (t < TP && kk < DT) ? a[((size_t)b * T_ + t) * DT + kk] : 0.f;
    A_s[t * LDA + 128 + kk] = f2bf(v);
  }
  __syncthreads();

  for (int nt = 0; nt < 32; ++nt) {
    const int n0 = nt * 64;
    const bool isQ = (n0 < DHN);
    const float* wsrc = isQ ? q_w : v_w;
    const float* bias = isQ ? q_b : v_b;
    const int nb = isQ ? n0 : (n0 - DHN);

    for (int idx = tid; idx < 160 * 64; idx += 256) {
      int k = idx >> 6, n = idx & 63;
      float v = (k < DD + DT) ? wsrc[(size_t)k * DHN + nb + n] : 0.f;
      BC_s[n * LDA + k] = f2bf(v);
    }
    __syncthreads();

    f32x4 acc[2][4];
#pragma unroll
    for (int mi = 0; mi < 2; ++mi)
#pragma unroll
      for (int ni = 0; ni < 4; ++ni) { f32x4 zz = {0.f,0.f,0.f,0.f}; acc[mi][ni] = zz; }
    const int mb = w * 32;
#pragma unroll
    for (int kc = 0; kc < 5; ++kc) {
      const int ko = kc * 32 + ((lane >> 4) << 3);
      short8v af[2], bf[4];
#pragma unroll
      for (int mi = 0; mi < 2; ++mi)
        af[mi] = *(const short8v*)&A_s[(mb + mi*16 + (lane & 15)) * LDA + ko];
#pragma unroll
      for (int ni = 0; ni < 4; ++ni)
        bf[ni] = *(const short8v*)&BC_s[(ni*16 + (lane & 15)) * LDA + ko];
#pragma unroll
      for (int mi = 0; mi < 2; ++mi)
#pragma unroll
        for (int ni = 0; ni < 4; ++ni)
          acc[mi][ni] = __builtin_amdgcn_mfma_f32_16x16x32_bf16(af[mi], bf[ni], acc[mi][ni], 0, 0, 0);
    }
    __syncthreads();

#pragma unroll
    for (int mi = 0; mi < 2; ++mi)
#pragma unroll
      for (int ni = 0; ni < 4; ++ni) {
        int cl = ni*16 + (lane & 15);
        float bb = bias[nb + cl];
#pragma unroll
        for (int q = 0; q < 4; ++q) {
          int t = mb + mi*16 + ((lane >> 4) << 2) + q;
          float vv = acc[mi][ni][q] + bb;
          if (isQ) vv = fmaxf(vv, 0.f);
          BC_s[t * 66 + cl] = f2bf(vv);
        }
      }
    __syncthreads();

    if (isQ) {
      // tile nt covers d chunk c = nt (16 d's); bytes: cl = 16k + 4j + h
      int c = nt;
      for (int idx = tid; idx < 512; idx += 256) {
        int t = idx >> 2, h = idx & 3;
        const unsigned short* base = &BC_s[t * 66 + h];
        uint4 u;
        u.x = pk4fp8(bf16u(base[ 0]), bf16u(base[ 4]), bf16u(base[ 8]), bf16u(base[12]));
        u.y = pk4fp8(bf16u(base[16]), bf16u(base[20]), bf16u(base[24]), bf16u(base[28]));
        u.z = pk4fp8(bf16u(base[32]), bf16u(base[36]), bf16u(base[40]), bf16u(base[44]));
        u.w = pk4fp8(bf16u(base[48]), bf16u(base[52]), bf16u(base[56]), bf16u(base[60]));
        Qf8[((size_t)b * 512 + idx) * 16 + c] = u;
      }
    } else {
      int j2b = (n0 - DHN) >> 1;
      for (int idx = tid; idx < 2048; idx += 256) {
        int n = idx >> 6, rem = idx & 63, j2l = rem >> 1, d = rem & 1;
        int cl = j2l * 2 + d;
        unsigned pk = pk4fp8(bf16u(BC_s[(4*n+0)*66 + cl]), bf16u(BC_s[(4*n+1)*66 + cl]),
                             bf16u(BC_s[(4*n+2)*66 + cl]), bf16u(BC_s[(4*n+3)*66 + cl]));
        Vf8[(((size_t)b * 32 + n) * 512 + j2b + j2l) * 2 + d] = pk;
      }
    }
    __syncthreads();
  }
}

// ---------------------------------------------------------------------------
// Kernel 3: 127-step recurrence.  One block per b, 512 threads (8 waves).
// Q fp8 in 16 named uint4 registers (64 VGPR payload -> fits the observed
// 128-VGPR cap at 512 thr).  V fp8 in 128 KB LDS.  All recurrent weights
// fp8 (x64 pre-scaled) in uint4/uint-per-lane coalesced layouts: streamed
// bytes/block/step drop 544 KB -> 208 KB (the R8 bottleneck).
// ---------------------------------------------------------------------------
__global__ __launch_bounds__(512)
void recur_kernel(
    const float* __restrict__ x, const float* __restrict__ bvec,
    const float* __restrict__ m, const float* __restrict__ eps,
    const float* __restrict__ bk_w, const float* __restrict__ bk_b,
    const float* __restrict__ bv_w, const float* __restrict__ bv_b,
    const float* __restrict__ hk_b, const float* __restrict__ hv_b,
    const float* __restrict__ mu1_w, const float* __restrict__ mu1_b,
    const float* __restrict__ sg1_w, const float* __restrict__ sg1_b,
    const float* __restrict__ mut_b, const float* __restrict__ sgt_b,
    const uint2* __restrict__ hvf, const unsigned* __restrict__ hkf,
    const unsigned* __restrict__ msf,
    const uint4* __restrict__ Qf8, const uint2* __restrict__ Vf8,
    float* __restrict__ out)
{
  const int b    = blockIdx.x;
  const int tid  = threadIdx.x;
  const int lane = tid & 63;
  const int wvid = tid >> 6;          // 0..7

  extern __shared__ __align__(16) unsigned ldsRaw[];
  uint2* ldsV = (uint2*)ldsRaw;       // [32][512] uint2 = 128 KB

  __shared__ __align__(16) float key_s[DH];
  __shared__ __align__(16) float sc[512];
  __shared__ __align__(16) float p_T[4][128];
  __shared__ __align__(16) float ht_s[DHN];
  __shared__ __align__(16) float red[8 * 64];
  __shared__ __align__(16) float z_s[DS];
  __shared__ __align__(16) float xb[DD + DB];
  __shared__ float mask_s[128];
  __shared__ __align__(16) float hkb_s[DH];
  __shared__ __align__(16) float hvb_s[DHN];
  __shared__ float mtb_s[DS], stb_s[DS];

  // ---- preload small constants ----
  if (tid < DD + DB) xb[tid] = (tid < DD) ? x[(size_t)b * T_ * DD + tid] : bvec[b * DB + (tid - DD)];
  if (tid >= 256) hkb_s[tid - 256] = hk_b[tid - 256];
  hvb_s[tid] = hv_b[tid]; hvb_s[tid + 512] = hv_b[tid + 512];
  if (tid < DS) { mtb_s[tid] = mut_b[tid]; stb_s[tid] = sgt_b[tid]; }
  ((float*)p_T)[tid] = 0.f;                 // covers all 4x128; t=127 stays 0

  // ---- mask[t] ----
  for (int t = wvid; t < TP; t += 8) {
    const float* mr = m + ((size_t)b * T_ + 1 + t) * DD;
    float s = mr[lane] + mr[lane + 64];
    for (int o = 1; o < 64; o <<= 1) s += __shfl_xor(s, o);
    if (lane == 0) mask_s[t] = (s > 0.f) ? 1.f : 0.f;
  }
  if (tid == 0) mask_s[127] = 0.f;

  // ---- stage V fp8 into LDS (one-time, coalesced) ----
  {
    const uint2* vp = Vf8 + (size_t)b * 16384 + tid;
#pragma unroll
    for (int i = 0; i < 32; ++i) ldsV[i * 512 + tid] = vp[i * 512];
  }

  // ---- Q row (t,h)=tid into 16 named uint4 registers (64 VGPR payload) ----
  const uint4* qrow = Qf8 + ((size_t)b * 512 + tid) * 16;
#define LDQ(c) uint4 qa##c = qrow[c];
  REP16(LDQ)
#undef LDQ
  __syncthreads();

  const int hW = tid >> 7;            // head of cols 2tid,2tid+1 (wave-uniform)
  const float invs = 1.f / 64.f;

  for (int st = 0; st < TP; ++st) {
    // ---------- key (tid<256) / val (cols 2tid,2tid+1 in regs) ----------
    float myv0, myv1;
    if (st == 0) {
      float a0 = bv_b[2*tid], a1 = bv_b[2*tid+1];
      for (int s = 0; s < DD + DB; ++s) {
        float xs = xb[s];
        const float* rr = bv_w + (size_t)s * DHN + 2*tid;
        a0 = fmaf(xs, rr[0], a0); a1 = fmaf(xs, rr[1], a1);
      }
      myv0 = a0; myv1 = a1;
      if (tid < 256) {
        float ak = bk_b[tid];
        for (int s = 0; s < DD + DB; ++s) ak = fmaf(xb[s], bk_w[s * DH + tid], ak);
        key_s[tid] = fmaxf(ak, 0.f);
      }
    } else {
      float a0 = 0.f, a1 = 0.f;
#pragma unroll
      for (int s4 = 0; s4 < 16; ++s4) {
        uint2 wv = hvf[s4 * 512 + tid];
        float4 zz = *(const float4*)&z_s[s4 * 4];
        f32x2 p0 = CVT8(wv.x, false), p1 = CVT8(wv.x, true);
        f32x2 p2 = CVT8(wv.y, false), p3 = CVT8(wv.y, true);
        a0 = fmaf(zz.x, p0.x, a0); a1 = fmaf(zz.x, p0.y, a1);
        a0 = fmaf(zz.y, p1.x, a0); a1 = fmaf(zz.y, p1.y, a1);
        a0 = fmaf(zz.z, p2.x, a0); a1 = fmaf(zz.z, p2.y, a1);
        a0 = fmaf(zz.w, p3.x, a0); a1 = fmaf(zz.w, p3.y, a1);
      }
      myv0 = fmaf(a0, invs, hvb_s[2*tid]);
      myv1 = fmaf(a1, invs, hvb_s[2*tid+1]);
      if (tid < 256) {
        float ak = 0.f;
#pragma unroll
        for (int s4 = 0; s4 < 16; ++s4) {
          unsigned wq = hkf[s4 * 256 + tid];
          float4 zz = *(const float4*)&z_s[s4 * 4];
          f32x2 q0 = CVT8(wq, false), q1 = CVT8(wq, true);
          ak = fmaf(zz.x, q0.x, ak); ak = fmaf(zz.y, q0.y, ak);
          ak = fmaf(zz.z, q1.x, ak); ak = fmaf(zz.w, q1.y, ak);
        }
        key_s[tid] = fmaxf(fmaf(ak, invs, hkb_s[tid]), 0.f);
      }
    }
    __syncthreads();

    // ---------- scores: thread r=tid, full 256-d row from Q registers ----------
    {
      float acc = 0.f;
#define SCD(wrd, kidx) { f32x2 f01 = CVT8((wrd), false); f32x2 f23 = CVT8((wrd), true); \
      float4 kk = *(const float4*)&key_s[(kidx) * 4]; \
      acc = fmaf(f01.x, kk.x, acc); acc = fmaf(f01.y, kk.y, acc); \
      acc = fmaf(f23.x, kk.z, acc); acc = fmaf(f23.y, kk.w, acc); }
#define SCC(c) { SCD(qa##c.x, (c)*4+0) SCD(qa##c.y, (c)*4+1) SCD(qa##c.z, (c)*4+2) SCD(qa##c.w, (c)*4+3) }
      REP16(SCC)
#undef SCC
#undef SCD
      sc[tid] = (mask_s[tid >> 2] > 0.f) ? acc * 0.0625f : -1e9f;
    }
    __syncthreads();

    // ---------- softmax over t, per head h = wave 0..3 (tid<256) ----------
    if (tid < 256) {
      int h = wvid, l = lane;
      float v1 = sc[l * 4 + h];
      float v2 = (l + 64 < TP) ? sc[(l + 64) * 4 + h] : -3.0e38f;
      float mm = fmaxf(v1, v2);
      for (int o = 1; o < 64; o <<= 1) mm = fmaxf(mm, __shfl_xor(mm, o));
      float e1 = __expf(v1 - mm);
      float e2 = (l + 64 < TP) ? __expf(v2 - mm) : 0.f;
      float ssum = e1 + e2;
      for (int o = 1; o < 64; o <<= 1) ssum += __shfl_xor(ssum, o);
      float inv = 1.f / ssum;
      p_T[h][l] = e1 * inv;
      if (l + 64 < TP) p_T[h][l + 64] = e2 * inv;
    }
    __syncthreads();

    // ---------- PV: cols 2tid,2tid+1 from LDS V; p_T reads broadcast ----------
    {
      float a0 = 0.f, a1 = 0.f;
#pragma unroll
      for (int n = 0; n < 32; ++n) {
        uint2 vv = ldsV[n * 512 + tid];
        float4 pp = *(const float4*)&p_T[hW][4 * n];
        f32x2 v0 = CVT8(vv.x, false), v1 = CVT8(vv.x, true);
        f32x2 w0 = CVT8(vv.y, false), w1 = CVT8(vv.y, true);
        a0 = fmaf(pp.x, v0.x, a0); a0 = fmaf(pp.y, v0.y, a0);
        a0 = fmaf(pp.z, v1.x, a0); a0 = fmaf(pp.w, v1.y, a0);
        a1 = fmaf(pp.x, w0.x, a1); a1 = fmaf(pp.y, w0.y, a1);
        a1 = fmaf(pp.z, w1.x, a1); a1 = fmaf(pp.w, w1.y, a1);
      }
      float2 hh;
      hh.x = fmaxf(0.5f * (a0 + myv0), 0.f);
      hh.y = fmaxf(0.5f * (a1 + myv1), 0.f);
      *(float2*)&ht_s[2 * tid] = hh;
    }
    __syncthreads();

    // ---------- mu/sg: k=tid&63, sel=(tid>>6)&1, g=tid>>7 (4 groups) ----------
    {
      int k = tid & 63, sel = (tid >> 6) & 1, g = tid >> 7;
      float acc = 0.f;
      if (st == 0) {
        const float* wsel = sel ? sg1_w : mu1_w;
        for (int jl = g * 256; jl < g * 256 + 256; ++jl)
          acc = fmaf(ht_s[jl], wsel[(size_t)jl * 64 + k], acc);
      } else {
        const unsigned* wp = msf + sel * 16384;
#pragma unroll 8
        for (int j4 = g * 64; j4 < g * 64 + 64; ++j4) {
          unsigned wm = wp[j4 * 64 + k];
          float4 hh = *(const float4*)&ht_s[j4 * 4];
          f32x2 f0 = CVT8(wm, false), f1 = CVT8(wm, true);
          acc = fmaf(hh.x, f0.x, acc); acc = fmaf(hh.y, f0.y, acc);
          acc = fmaf(hh.z, f1.x, acc); acc = fmaf(hh.w, f1.y, acc);
        }
      }
      red[(sel * 4 + g) * 64 + k] = acc;
    }
    __syncthreads();

    if (tid < 64) {
      float wsc = (st == 0) ? 1.f : invs;
      float mu = ((st == 0) ? mu1_b[tid] : mtb_s[tid])
               + (red[tid] + red[64 + tid] + red[128 + tid] + red[192 + tid]) * wsc;
      float sl = ((st == 0) ? sg1_b[tid] : stb_s[tid])
               + (red[256 + tid] + red[320 + tid] + red[384 + tid] + red[448 + tid]) * wsc;
      float sg = softplus_f(sl);
      float z  = fmaf(sg, eps[((size_t)st * BS + b) * 64 + tid], mu);
      size_t o0 = ((size_t)b * TP + st) * 64 + tid;
      out[o0] = z; out[OFFV + o0] = mu; out[2ull * OFFV + o0] = sg;
      z_s[tid] = z;
    }
    __syncthreads();
  }
}

// ---------------------------------------------------------------------------
extern "C" void kernel_launch(void* const* d_in, const int* in_sizes, int n_in,
                              void* d_out, int out_size, void* d_ws, size_t ws_size,
                              hipStream_t stream) {
  const float* x    = (const float*)d_in[0];
  const float* a    = (const float*)d_in[1];
  const float* m    = (const float*)d_in[2];
  const float* bvec = (const float*)d_in[3];
  const float* eps  = (const float*)d_in[4];
  const float* bk_w = (const float*)d_in[5];
  const float* bk_b = (const float*)d_in[6];
  const float* bv_w = (const float*)d_in[7];
  const float* bv_b = (const float*)d_in[8];
  const float* q_w  = (const float*)d_in[9];
  const float* q_b  = (const float*)d_in[10];
  const float* v_w  = (const float*)d_in[11];
  const float* v_b  = (const float*)d_in[12];
  const float* hk_w = (const float*)d_in[13];
  const float* hk_b = (const float*)d_in[14];
  const float* hv_w = (const float*)d_in[15];
  const float* hv_b = (const float*)d_in[16];
  const float* mu1_w= (const float*)d_in[17];
  const float* mu1_b= (const float*)d_in[18];
  const float* sg1_w= (const float*)d_in[19];
  const float* sg1_b= (const float*)d_in[20];
  const float* mut_w= (const float*)d_in[21];
  const float* mut_b= (const float*)d_in[22];
  const float* sgt_w= (const float*)d_in[23];
  const float* sgt_b= (const float*)d_in[24];

  // workspace: Qf8 32MB | Vf8 32MB | hvf 64KB | hkf 16KB | msf 128KB
  char* ws = (char*)d_ws;
  uint4*    Qf8 = (uint4*)ws;
  unsigned* Vf8 = (unsigned*)(ws + (32ull << 20));
  uint2*    hvf = (uint2*)(ws + (64ull << 20));
  unsigned* hkf = (unsigned*)(ws + (64ull << 20) + (64u << 10));
  unsigned* msf = (unsigned*)(ws + (64ull << 20) + (80u << 10));

  pack_w_kernel<<<dim3(128), dim3(256), 0, stream>>>(hk_w, hv_w, mut_w, sgt_w,
                                                     hvf, hkf, msf);
  proj_kernel<<<dim3(256), dim3(256), 0, stream>>>(x, a, q_w, q_b, v_w, v_b,
                                                   Qf8, Vf8);
  recur_kernel<<<dim3(256), dim3(512), 131072, stream>>>(x, bvec, m, eps,
      bk_w, bk_b, bv_w, bv_b, hk_b, hv_b,
      mu1_w, mu1_b, sg1_w, sg1_b, mut_b, sgt_b,
      hvf, hkf, msf, Qf8, (const uint2*)Vf8, (float*)d_out);
}